// Round 5
// baseline (526.997 us; speedup 1.0000x reference)
//
#include <hip/hip_runtime.h>
#include <hip/hip_bf16.h>
#include <stdint.h>

// Problem-fixed shapes
#define B_ 8
#define S_ 2048
#define F_ 2048
#define M_ (B_*S_)   // 16384 rows (b*S+s)
#define K_ F_
#define N_ F_

typedef __attribute__((ext_vector_type(4))) float f32x4;
typedef __attribute__((ext_vector_type(8))) short short8;

// ---------- helpers ----------
__device__ __forceinline__ unsigned short f2bf(float f){
  unsigned u = __float_as_uint(f);
  u += 0x7FFFu + ((u >> 16) & 1u);   // round-to-nearest-even
  return (unsigned short)(u >> 16);
}

__device__ __forceinline__ void gload16(const void* g, const void* l){
  __builtin_amdgcn_global_load_lds(
      (const __attribute__((address_space(1))) void*)g,
      (__attribute__((address_space(3))) void*)l,
      16, 0, 0);
}

__device__ __forceinline__ float waveReduce(float v){
  #pragma unroll
  for (int off = 32; off; off >>= 1) v += __shfl_down(v, off, 64);
  return v;
}

__device__ __forceinline__ float blockReduceAll(float v, float* sbuf){
  v = waveReduce(v);
  int lane = threadIdx.x & 63, w = threadIdx.x >> 6;
  __syncthreads();
  if (lane == 0) sbuf[w] = v;
  __syncthreads();
  return sbuf[0] + sbuf[1] + sbuf[2] + sbuf[3];
}

// ---------- 1) scale = mean(|W|) ----------
__global__ __launch_bounds__(256) void k_abs1(const float* __restrict__ W, float* __restrict__ part){
  __shared__ float sb[4];
  size_t idx = ((size_t)blockIdx.x * 256 + threadIdx.x) * 4;
  f32x4 v = *(const f32x4*)(W + idx);
  float s = fabsf(v[0]) + fabsf(v[1]) + fabsf(v[2]) + fabsf(v[3]);
  s = blockReduceAll(s, sb);
  if (threadIdx.x == 0) part[blockIdx.x] = s;
}

__global__ __launch_bounds__(256) void k_abs2(const float* __restrict__ part, float* __restrict__ scalep){
  __shared__ float sb[4];
  float s = 0.f;
  int t = threadIdx.x;
  #pragma unroll
  for (int i = 0; i < 16; i++) s += part[t + i*256];   // 4096 partials
  s = blockReduceAll(s, sb);
  if (t == 0) scalep[0] = s * (1.0f / ((float)F_ * (float)F_));
}

// ---------- 2) quantize W -> ternary bf16, transposed: BT[g][f] ----------
__global__ __launch_bounds__(256) void k_quantT(const float* __restrict__ W, unsigned short* __restrict__ BT,
                                                const float* __restrict__ scalep){
  __shared__ float tile[32][33];
  int gx = blockIdx.x * 32;
  int fy = blockIdx.y * 32;
  int tx = threadIdx.x & 31, ty = threadIdx.x >> 5;
  float inv = 1.0f / (scalep[0] + 1e-8f);
  #pragma unroll
  for (int i = 0; i < 4; i++){
    int f = fy + ty + i*8;
    tile[ty + i*8][tx] = W[(size_t)f * F_ + gx + tx];
  }
  __syncthreads();
  #pragma unroll
  for (int i = 0; i < 4; i++){
    int g = gx + ty + i*8;
    float w = tile[tx][ty + i*8];
    float t = rintf(w * inv);
    t = fminf(1.0f, fmaxf(-1.0f, t));
    BT[(size_t)g * K_ + fy + tx] = f2bf(t);
  }
}

// ---------- 3) fused front-end: one pass over X ----------
// per block: 32 rows of one batch b. Produces XH (bf16), la_raw (row dot), ra partials.
__global__ __launch_bounds__(256) void k_front(const float* __restrict__ X, const float* __restrict__ wl,
                                               const float* __restrict__ bl, const float* __restrict__ wrt,
                                               unsigned short* __restrict__ XH, float* __restrict__ la_raw,
                                               float* __restrict__ ra_raw){
  __shared__ float lap[4][32];
  int t = threadIdx.x, w = t >> 6, lane = t & 63;
  int r0 = blockIdx.x * 32;
  int b  = r0 >> 11;                 // r0 / S_
  int f0 = t * 8;
  f32x4 wl0 = *(const f32x4*)(wl + f0);
  f32x4 wl1 = *(const f32x4*)(wl + f0 + 4);
  float racc[8];
  #pragma unroll
  for (int j = 0; j < 8; j++) racc[j] = 0.f;

  for (int rr = 0; rr < 32; ++rr){
    int row = r0 + rr;
    const float* xr = X + (size_t)row * F_ + f0;
    f32x4 v0 = *(const f32x4*)(xr);
    f32x4 v1 = *(const f32x4*)(xr + 4);
    // bf16 conversion/store
    ushort4 p0, p1;
    p0.x = f2bf(v0[0]); p0.y = f2bf(v0[1]); p0.z = f2bf(v0[2]); p0.w = f2bf(v0[3]);
    p1.x = f2bf(v1[0]); p1.y = f2bf(v1[1]); p1.z = f2bf(v1[2]); p1.w = f2bf(v1[3]);
    unsigned short* xh = XH + (size_t)row * F_ + f0;
    *(ushort4*)(xh)     = p0;
    *(ushort4*)(xh + 4) = p1;
    // left-attn dot partial
    float dot = v0[0]*wl0[0] + v0[1]*wl0[1] + v0[2]*wl0[2] + v0[3]*wl0[3]
              + v1[0]*wl1[0] + v1[1]*wl1[1] + v1[2]*wl1[2] + v1[3]*wl1[3];
    dot = waveReduce(dot);
    if (lane == 0) lap[w][rr] = dot;
    // right-attn partial (per-f accumulate; f unique per (t,j) within block)
    float wsr = wrt[row & (S_-1)];
    racc[0] += v0[0]*wsr; racc[1] += v0[1]*wsr; racc[2] += v0[2]*wsr; racc[3] += v0[3]*wsr;
    racc[4] += v1[0]*wsr; racc[5] += v1[1]*wsr; racc[6] += v1[2]*wsr; racc[7] += v1[3]*wsr;
  }
  __syncthreads();
  if (t < 32)
    la_raw[r0 + t] = lap[0][t] + lap[1][t] + lap[2][t] + lap[3][t] + bl[0];
  float* rb = ra_raw + b * F_ + f0;
  #pragma unroll
  for (int j = 0; j < 8; j++) atomicAdd(&rb[j], racc[j]);
}

// ---------- 5) LN over S, relu, x/(x+eps) ----------
__global__ __launch_bounds__(256) void k_ln_la(const float* __restrict__ la_raw, float* __restrict__ la){
  __shared__ float sb[4];
  int b = blockIdx.x;
  const float* p = la_raw + b * S_;
  int t = threadIdx.x;
  float v[8]; float s = 0.f, s2 = 0.f;
  #pragma unroll
  for (int i = 0; i < 8; i++){ v[i] = p[t + i*256]; s += v[i]; s2 += v[i]*v[i]; }
  s  = blockReduceAll(s,  sb);
  s2 = blockReduceAll(s2, sb);
  float mu  = s * (1.0f / S_);
  float var = s2 * (1.0f / S_) - mu*mu;
  float rstd = 1.0f / sqrtf(var + 1e-5f);
  #pragma unroll
  for (int i = 0; i < 8; i++){
    float x = (v[i] - mu) * rstd;
    x = fmaxf(x, 0.0f);
    la[b * S_ + t + i*256] = x / (x + 1e-6f);
  }
}

// ---------- 6) LN over F, relu, normalize by sum ----------
__global__ __launch_bounds__(256) void k_ln_ra(const float* __restrict__ ra_raw, const float* __restrict__ br,
                                               float* __restrict__ ra){
  __shared__ float sb[4];
  int b = blockIdx.x;
  const float* p = ra_raw + b * F_;
  int t = threadIdx.x;
  float bb = br[0];
  float v[8]; float s = 0.f, s2 = 0.f;
  #pragma unroll
  for (int i = 0; i < 8; i++){ v[i] = p[t + i*256] + bb; s += v[i]; s2 += v[i]*v[i]; }
  s  = blockReduceAll(s,  sb);
  s2 = blockReduceAll(s2, sb);
  float mu  = s * (1.0f / F_);
  float var = s2 * (1.0f / F_) - mu*mu;
  float rstd = 1.0f / sqrtf(var + 1e-5f);
  float r[8]; float sr = 0.f;
  #pragma unroll
  for (int i = 0; i < 8; i++){ r[i] = fmaxf((v[i] - mu) * rstd, 0.0f); sr += r[i]; }
  sr = blockReduceAll(sr, sb);
  float invs = 1.0f / (sr + 1e-6f);
  #pragma unroll
  for (int i = 0; i < 8; i++) ra[b * F_ + t + i*256] = r[i] * invs;
}

// ---------- 7) GEMM: bf16 MFMA 16x16x32, 128x128 tile, 2-phase double-buffered ----------
// A = XH [M][K] bf16; B^T = BT [N][K] bf16.
// LDS per buffer: A[128][32] 8KB | B[128][32] 8KB; 2 buffers = 32KB.
// Swizzle (both-sides, rule #21): chunk (row r, pos p in 0..3) holds global
// [r][p ^ ((r>>1)&3)] -> 8 distinct 16B-quads over 8 consecutive rows.
__global__ __launch_bounds__(256) void k_gemm(
    const unsigned short* __restrict__ A, const unsigned short* __restrict__ BT,
    const float* __restrict__ X, const float* __restrict__ la, const float* __restrict__ ra,
    const float* __restrict__ bv, const float* __restrict__ alphap, const float* __restrict__ scalep,
    float* __restrict__ Out)
{
  __shared__ __align__(128) char lds[32768];
  const int NBX = N_ / 128;                    // 16
  int tid = threadIdx.x;
  int bid = blockIdx.x;
  const int nwg = (M_/128) * (N_/128);         // 2048, divisible by 8
  int cpx = nwg >> 3;
  int swz = (bid & 7) * cpx + (bid >> 3);
  int brow = swz / NBX, bcol = swz % NBX;
  int row0 = brow * 128, col0 = bcol * 128;

  int w = tid >> 6, lane = tid & 63;
  int wr = w >> 1, wc = w & 1;                 // 2x2 waves, each 64x64
  int lrow = lane & 15, kgrp = lane >> 4;

  f32x4 acc[4][4];
  #pragma unroll
  for (int m = 0; m < 4; m++)
    #pragma unroll
    for (int n = 0; n < 4; n++) acc[m][n] = (f32x4)(0.0f);

  // staging source addresses (pre-swizzled global, linear LDS dest)
  int c0 = tid, c1 = tid + 256;
  int ar0 = c0 >> 2, ak0 = (((c0 & 3) ^ ((ar0 >> 1) & 3)) << 3);
  int ar1 = c1 >> 2, ak1 = (((c1 & 3) ^ ((ar1 >> 1) & 3)) << 3);
  const unsigned short* Ap0 = A  + (size_t)(row0 + ar0) * K_ + ak0;
  const unsigned short* Ap1 = A  + (size_t)(row0 + ar1) * K_ + ak1;
  const unsigned short* Bp0 = BT + (size_t)(col0 + ar0) * K_ + ak0;
  const unsigned short* Bp1 = BT + (size_t)(col0 + ar1) * K_ + ak1;
  int stoff = w * 1024;                        // + lane*16 implicit

  // ds_read offsets (swizzled)
  int aoff[4], boff[4];
  #pragma unroll
  for (int m = 0; m < 4; m++){
    int r  = wr*64 + m*16 + lrow;
    aoff[m] = r*64 + ((kgrp ^ ((r >> 1) & 3)) << 4);
    int rc = wc*64 + m*16 + lrow;
    boff[m] = 8192 + rc*64 + ((kgrp ^ ((rc >> 1) & 3)) << 4);
  }

  // prologue: stage tile 0 into buffer 0
  {
    char* base = lds;
    gload16(Ap0, base + stoff);
    gload16(Ap1, base + 4096 + stoff);
    gload16(Bp0, base + 8192 + stoff);
    gload16(Bp1, base + 12288 + stoff);
  }
  asm volatile("s_waitcnt vmcnt(0)" ::: "memory");
  __syncthreads();

  int cur = 0;
  for (int kt = 0; kt < K_/32; ++kt){
    // issue next-tile loads into the other buffer (overlap with compute)
    if (kt < K_/32 - 1){
      char* nb = lds + (cur ^ 1) * 16384;
      const unsigned short* a0 = Ap0 + (kt+1)*32;
      const unsigned short* a1 = Ap1 + (kt+1)*32;
      const unsigned short* b0 = Bp0 + (kt+1)*32;
      const unsigned short* b1 = Bp1 + (kt+1)*32;
      gload16(a0, nb + stoff);
      gload16(a1, nb + 4096 + stoff);
      gload16(b0, nb + 8192 + stoff);
      gload16(b1, nb + 12288 + stoff);
    }
    const char* bb = lds + cur * 16384;
    short8 af[4], bfr[4];
    #pragma unroll
    for (int m = 0; m < 4; m++) af[m]  = *(const short8*)(bb + aoff[m]);
    #pragma unroll
    for (int n = 0; n < 4; n++) bfr[n] = *(const short8*)(bb + boff[n]);
    __builtin_amdgcn_s_setprio(1);
    #pragma unroll
    for (int m = 0; m < 4; m++)
      #pragma unroll
      for (int n = 0; n < 4; n++)
        acc[m][n] = __builtin_amdgcn_mfma_f32_16x16x32_bf16(af[m], bfr[n], acc[m][n], 0, 0, 0);
    __builtin_amdgcn_s_setprio(0);
    asm volatile("s_waitcnt vmcnt(0)" ::: "memory");
    __syncthreads();
    cur ^= 1;
  }

  // epilogue: out = (1-a)*x + a * la[row] * (acc*scale + b_v[col]) * ra[b][col]
  float a = alphap[0];
  float scale = scalep[0];
  float oma = 1.0f - a;
  int bidx = row0 >> 11;
  const float* rab = ra + bidx * F_;
  #pragma unroll
  for (int m = 0; m < 4; m++){
    int rbase = row0 + wr*64 + m*16 + (lane >> 4) * 4;
    float lav[4];
    #pragma unroll
    for (int r = 0; r < 4; r++) lav[r] = la[rbase + r];
    #pragma unroll
    for (int n = 0; n < 4; n++){
      int col = col0 + wc*64 + n*16 + (lane & 15);
      float rav = rab[col];
      float bvv = bv[col];
      #pragma unroll
      for (int r = 0; r < 4; r++){
        int row = rbase + r;
        float v = acc[m][n][r] * scale + bvv;
        size_t idx = (size_t)row * N_ + col;
        Out[idx] = oma * X[idx] + a * lav[r] * v * rav;
      }
    }
  }
}

// ---------- launch ----------
extern "C" void kernel_launch(void* const* d_in, const int* in_sizes, int n_in,
                              void* d_out, int out_size, void* d_ws, size_t ws_size,
                              hipStream_t stream){
  const float* x     = (const float*)d_in[0];
  const float* Wv    = (const float*)d_in[3];
  const float* bv    = (const float*)d_in[4];
  const float* wl    = (const float*)d_in[5];
  const float* bl    = (const float*)d_in[6];
  const float* wrt   = (const float*)d_in[7];
  const float* br    = (const float*)d_in[8];
  const float* alpha = (const float*)d_in[9];
  float* out = (float*)d_out;

  char* ws = (char*)d_ws;
  unsigned short* XH = (unsigned short*)(ws);              // 67,108,864 B
  unsigned short* BT = (unsigned short*)(ws + 67108864);   //  8,388,608 B
  float* la_raw = (float*)(ws + 75497472);                 // 65,536 B
  float* la     = (float*)(ws + 75563008);                 // 65,536 B
  float* ra_raw = (float*)(ws + 75628544);                 // 65,536 B
  float* ra     = (float*)(ws + 75694080);                 // 65,536 B
  float* part   = (float*)(ws + 75759616);                 // 16,384 B
  float* scalep = (float*)(ws + 75776000);                 //    256 B

  hipMemsetAsync(ra_raw, 0, B_ * F_ * sizeof(float), stream);
  k_abs1<<<4096, 256, 0, stream>>>(Wv, part);
  k_abs2<<<1, 256, 0, stream>>>(part, scalep);
  k_quantT<<<dim3(F_/32, F_/32), 256, 0, stream>>>(Wv, BT, scalep);
  k_front<<<M_/32, 256, 0, stream>>>(x, wl, bl, wrt, XH, la_raw, ra_raw);
  k_ln_la<<<B_, 256, 0, stream>>>(la_raw, la);
  k_ln_ra<<<B_, 256, 0, stream>>>(ra_raw, br, ra);
  k_gemm<<<2048, 256, 0, stream>>>(XH, BT, x, la, ra, bv, alpha, scalep, out);
}

// Round 6
// 465.799 us; speedup vs baseline: 1.1314x; 1.1314x over previous
//
#include <hip/hip_runtime.h>
#include <hip/hip_bf16.h>
#include <stdint.h>

// Problem-fixed shapes
#define B_ 8
#define S_ 2048
#define F_ 2048
#define M_ (B_*S_)   // 16384 rows (b*S+s)
#define K_ F_
#define N_ F_

typedef __attribute__((ext_vector_type(4))) float f32x4;
typedef __attribute__((ext_vector_type(8))) short short8;

// ---------- helpers ----------
__device__ __forceinline__ unsigned short f2bf(float f){
  unsigned u = __float_as_uint(f);
  u += 0x7FFFu + ((u >> 16) & 1u);   // round-to-nearest-even
  return (unsigned short)(u >> 16);
}

__device__ __forceinline__ void gload16(const void* g, const void* l){
  __builtin_amdgcn_global_load_lds(
      (const __attribute__((address_space(1))) void*)g,
      (__attribute__((address_space(3))) void*)l,
      16, 0, 0);
}

__device__ __forceinline__ float waveReduce(float v){
  #pragma unroll
  for (int off = 32; off; off >>= 1) v += __shfl_down(v, off, 64);
  return v;
}

__device__ __forceinline__ float blockReduceAll(float v, float* sbuf){
  v = waveReduce(v);
  int lane = threadIdx.x & 63, w = threadIdx.x >> 6;
  __syncthreads();
  if (lane == 0) sbuf[w] = v;
  __syncthreads();
  return sbuf[0] + sbuf[1] + sbuf[2] + sbuf[3];
}

// ---------- 1) scale = mean(|W|) ----------
__global__ __launch_bounds__(256) void k_abs1(const float* __restrict__ W, float* __restrict__ part){
  __shared__ float sb[4];
  size_t idx = ((size_t)blockIdx.x * 256 + threadIdx.x) * 4;
  f32x4 v = *(const f32x4*)(W + idx);
  float s = fabsf(v[0]) + fabsf(v[1]) + fabsf(v[2]) + fabsf(v[3]);
  s = blockReduceAll(s, sb);
  if (threadIdx.x == 0) part[blockIdx.x] = s;
}

__global__ __launch_bounds__(256) void k_abs2(const float* __restrict__ part, float* __restrict__ scalep){
  __shared__ float sb[4];
  float s = 0.f;
  int t = threadIdx.x;
  #pragma unroll
  for (int i = 0; i < 16; i++) s += part[t + i*256];   // 4096 partials
  s = blockReduceAll(s, sb);
  if (t == 0) scalep[0] = s * (1.0f / ((float)F_ * (float)F_));
}

// ---------- 2) quantize W -> ternary bf16, transposed: BT[g][f] ----------
__global__ __launch_bounds__(256) void k_quantT(const float* __restrict__ W, unsigned short* __restrict__ BT,
                                                const float* __restrict__ scalep){
  __shared__ float tile[32][33];
  int gx = blockIdx.x * 32;
  int fy = blockIdx.y * 32;
  int tx = threadIdx.x & 31, ty = threadIdx.x >> 5;
  float inv = 1.0f / (scalep[0] + 1e-8f);
  #pragma unroll
  for (int i = 0; i < 4; i++){
    int f = fy + ty + i*8;
    tile[ty + i*8][tx] = W[(size_t)f * F_ + gx + tx];
  }
  __syncthreads();
  #pragma unroll
  for (int i = 0; i < 4; i++){
    int g = gx + ty + i*8;
    float w = tile[tx][ty + i*8];
    float t = rintf(w * inv);
    t = fminf(1.0f, fmaxf(-1.0f, t));
    BT[(size_t)g * K_ + fy + tx] = f2bf(t);
  }
}

// ---------- 3) fused front-end: one pass over X ----------
__global__ __launch_bounds__(256) void k_front(const float* __restrict__ X, const float* __restrict__ wl,
                                               const float* __restrict__ bl, const float* __restrict__ wrt,
                                               unsigned short* __restrict__ XH, float* __restrict__ la_raw,
                                               float* __restrict__ ra_raw){
  __shared__ float lap[4][32];
  int t = threadIdx.x, w = t >> 6, lane = t & 63;
  int r0 = blockIdx.x * 32;
  int b  = r0 >> 11;                 // r0 / S_
  int f0 = t * 8;
  f32x4 wl0 = *(const f32x4*)(wl + f0);
  f32x4 wl1 = *(const f32x4*)(wl + f0 + 4);
  float racc[8];
  #pragma unroll
  for (int j = 0; j < 8; j++) racc[j] = 0.f;

  for (int rr = 0; rr < 32; rr += 2){
    int rowA = r0 + rr, rowB = r0 + rr + 1;
    const float* xrA = X + (size_t)rowA * F_ + f0;
    const float* xrB = X + (size_t)rowB * F_ + f0;
    f32x4 a0 = *(const f32x4*)(xrA);
    f32x4 a1 = *(const f32x4*)(xrA + 4);
    f32x4 b0 = *(const f32x4*)(xrB);
    f32x4 b1 = *(const f32x4*)(xrB + 4);
    // bf16 conversion/store
    ushort4 pa0, pa1, pb0, pb1;
    pa0.x = f2bf(a0[0]); pa0.y = f2bf(a0[1]); pa0.z = f2bf(a0[2]); pa0.w = f2bf(a0[3]);
    pa1.x = f2bf(a1[0]); pa1.y = f2bf(a1[1]); pa1.z = f2bf(a1[2]); pa1.w = f2bf(a1[3]);
    pb0.x = f2bf(b0[0]); pb0.y = f2bf(b0[1]); pb0.z = f2bf(b0[2]); pb0.w = f2bf(b0[3]);
    pb1.x = f2bf(b1[0]); pb1.y = f2bf(b1[1]); pb1.z = f2bf(b1[2]); pb1.w = f2bf(b1[3]);
    unsigned short* xhA = XH + (size_t)rowA * F_ + f0;
    unsigned short* xhB = XH + (size_t)rowB * F_ + f0;
    *(ushort4*)(xhA)     = pa0;
    *(ushort4*)(xhA + 4) = pa1;
    *(ushort4*)(xhB)     = pb0;
    *(ushort4*)(xhB + 4) = pb1;
    // left-attn dot partials (two independent shfl chains -> ILP)
    float dotA = a0[0]*wl0[0] + a0[1]*wl0[1] + a0[2]*wl0[2] + a0[3]*wl0[3]
               + a1[0]*wl1[0] + a1[1]*wl1[1] + a1[2]*wl1[2] + a1[3]*wl1[3];
    float dotB = b0[0]*wl0[0] + b0[1]*wl0[1] + b0[2]*wl0[2] + b0[3]*wl0[3]
               + b1[0]*wl1[0] + b1[1]*wl1[1] + b1[2]*wl1[2] + b1[3]*wl1[3];
    #pragma unroll
    for (int off = 32; off; off >>= 1){
      dotA += __shfl_down(dotA, off, 64);
      dotB += __shfl_down(dotB, off, 64);
    }
    if (lane == 0){ lap[w][rr] = dotA; lap[w][rr+1] = dotB; }
    // right-attn partials
    float wsA = wrt[rowA & (S_-1)], wsB = wrt[rowB & (S_-1)];
    racc[0] += a0[0]*wsA + b0[0]*wsB; racc[1] += a0[1]*wsA + b0[1]*wsB;
    racc[2] += a0[2]*wsA + b0[2]*wsB; racc[3] += a0[3]*wsA + b0[3]*wsB;
    racc[4] += a1[0]*wsA + b1[0]*wsB; racc[5] += a1[1]*wsA + b1[1]*wsB;
    racc[6] += a1[2]*wsA + b1[2]*wsB; racc[7] += a1[3]*wsA + b1[3]*wsB;
  }
  __syncthreads();
  if (t < 32)
    la_raw[r0 + t] = lap[0][t] + lap[1][t] + lap[2][t] + lap[3][t] + bl[0];
  float* rb = ra_raw + b * F_ + f0;
  #pragma unroll
  for (int j = 0; j < 8; j++) atomicAdd(&rb[j], racc[j]);
}

// ---------- 4) merged LN: blocks 0..7 = la over S; blocks 8..15 = ra over F ----------
__global__ __launch_bounds__(256) void k_ln(const float* __restrict__ la_raw, const float* __restrict__ ra_raw,
                                            const float* __restrict__ br, float* __restrict__ la,
                                            float* __restrict__ ra){
  __shared__ float sb[4];
  int blk = blockIdx.x;
  bool isRa = blk >= 8;
  int b = blk & 7;
  const float* p = isRa ? (ra_raw + b * F_) : (la_raw + b * S_);
  int t = threadIdx.x;
  float bb = isRa ? br[0] : 0.0f;
  float v[8]; float s = 0.f, s2 = 0.f;
  #pragma unroll
  for (int i = 0; i < 8; i++){ v[i] = p[t + i*256] + bb; s += v[i]; s2 += v[i]*v[i]; }
  s  = blockReduceAll(s,  sb);
  s2 = blockReduceAll(s2, sb);
  float mu  = s * (1.0f / 2048.0f);
  float var = s2 * (1.0f / 2048.0f) - mu*mu;
  float rstd = 1.0f / sqrtf(var + 1e-5f);
  float r[8]; float sr = 0.f;
  #pragma unroll
  for (int i = 0; i < 8; i++){ r[i] = fmaxf((v[i] - mu) * rstd, 0.0f); sr += r[i]; }
  if (isRa){
    sr = blockReduceAll(sr, sb);
    float invs = 1.0f / (sr + 1e-6f);
    #pragma unroll
    for (int i = 0; i < 8; i++) ra[b * F_ + t + i*256] = r[i] * invs;
  } else {
    #pragma unroll
    for (int i = 0; i < 8; i++) la[b * S_ + t + i*256] = r[i] / (r[i] + 1e-6f);
  }
}

// ---------- 5) GEMM: bf16 MFMA 16x16x32, 128x128 tile, depth-3 pipeline ----------
// A = XH [M][K] bf16; B^T = BT [N][K] bf16.
// 4 LDS buffers x 16KB (A 8KB | B 8KB) = 64KB. Counted vmcnt (T3+T4):
// at iter kt, stage tile kt+3, wait vmcnt(8) -> tile kt+1 landed; raw s_barrier
// (no drain). Buffer staged at kt was last read at kt-1; those ds_reads are
// register-consumed by kt-1's MFMAs before its barrier -> no race.
// Swizzle (both-sides): quad p of row r holds global quad p ^ ((r>>1)&3).
__global__ __launch_bounds__(256) void k_gemm(
    const unsigned short* __restrict__ A, const unsigned short* __restrict__ BT,
    const float* __restrict__ X, const float* __restrict__ la, const float* __restrict__ ra,
    const float* __restrict__ bv, const float* __restrict__ alphap, const float* __restrict__ scalep,
    float* __restrict__ Out)
{
  __shared__ __align__(128) char lds[65536];
  const int NBX = N_ / 128;                    // 16
  const int NT  = K_ / 32;                     // 64
  int tid = threadIdx.x;
  int bid = blockIdx.x;
  const int nwg = (M_/128) * (N_/128);         // 2048, divisible by 8
  int cpx = nwg >> 3;
  int swz = (bid & 7) * cpx + (bid >> 3);
  int brow = swz / NBX, bcol = swz % NBX;
  int row0 = brow * 128, col0 = bcol * 128;

  int w = tid >> 6, lane = tid & 63;
  int wr = w >> 1, wc = w & 1;                 // 2x2 waves, each 64x64
  int lrow = lane & 15, kgrp = lane >> 4;

  f32x4 acc[4][4];
  #pragma unroll
  for (int m = 0; m < 4; m++)
    #pragma unroll
    for (int n = 0; n < 4; n++) acc[m][n] = (f32x4)(0.0f);

  // staging source addresses (pre-swizzled global, linear LDS dest)
  int c0 = tid, c1 = tid + 256;
  int ar0 = c0 >> 2, ak0 = (((c0 & 3) ^ ((ar0 >> 1) & 3)) << 3);
  int ar1 = c1 >> 2, ak1 = (((c1 & 3) ^ ((ar1 >> 1) & 3)) << 3);
  const unsigned short* Ap0 = A  + (size_t)(row0 + ar0) * K_ + ak0;
  const unsigned short* Ap1 = A  + (size_t)(row0 + ar1) * K_ + ak1;
  const unsigned short* Bp0 = BT + (size_t)(col0 + ar0) * K_ + ak0;
  const unsigned short* Bp1 = BT + (size_t)(col0 + ar1) * K_ + ak1;
  int stoff = w * 1024;                        // + lane*16 implicit

  // ds_read offsets (swizzled)
  int aoff[4], boff[4];
  #pragma unroll
  for (int m = 0; m < 4; m++){
    int r  = wr*64 + m*16 + lrow;
    aoff[m] = r*64 + ((kgrp ^ ((r >> 1) & 3)) << 4);
    int rc = wc*64 + m*16 + lrow;
    boff[m] = 8192 + rc*64 + ((kgrp ^ ((rc >> 1) & 3)) << 4);
  }

#define STAGE(T) { \
    char* nb_ = lds + ((T) & 3) * 16384; \
    gload16(Ap0 + (size_t)(T)*32, nb_ + stoff); \
    gload16(Ap1 + (size_t)(T)*32, nb_ + 4096 + stoff); \
    gload16(Bp0 + (size_t)(T)*32, nb_ + 8192 + stoff); \
    gload16(Bp1 + (size_t)(T)*32, nb_ + 12288 + stoff); \
  }

  // prologue: 3 tiles in flight
  STAGE(0); STAGE(1); STAGE(2);
  asm volatile("s_waitcnt vmcnt(8)" ::: "memory");   // tile 0 landed
  __builtin_amdgcn_s_barrier();

  for (int kt = 0; kt < NT; ++kt){
    if (kt + 3 < NT) STAGE(kt + 3);
    const char* bb = lds + (kt & 3) * 16384;
    short8 af[4], bfr[4];
    #pragma unroll
    for (int m = 0; m < 4; m++) af[m]  = *(const short8*)(bb + aoff[m]);
    #pragma unroll
    for (int n = 0; n < 4; n++) bfr[n] = *(const short8*)(bb + boff[n]);
    __builtin_amdgcn_s_setprio(1);
    #pragma unroll
    for (int m = 0; m < 4; m++)
      #pragma unroll
      for (int n = 0; n < 4; n++)
        acc[m][n] = __builtin_amdgcn_mfma_f32_16x16x32_bf16(af[m], bfr[n], acc[m][n], 0, 0, 0);
    __builtin_amdgcn_s_setprio(0);
    if (kt + 3 < NT)      { asm volatile("s_waitcnt vmcnt(8)" ::: "memory"); }  // tile kt+1 landed
    else if (kt + 2 < NT) { asm volatile("s_waitcnt vmcnt(4)" ::: "memory"); }
    else if (kt + 1 < NT) { asm volatile("s_waitcnt vmcnt(0)" ::: "memory"); }
    if (kt + 1 < NT) __builtin_amdgcn_s_barrier();
  }
#undef STAGE

  // epilogue: out = (1-a)*x + a * la[row] * (acc*scale + b_v[col]) * ra[b][col]
  float a = alphap[0];
  float scale = scalep[0];
  float oma = 1.0f - a;
  int bidx = row0 >> 11;
  const float* rab = ra + bidx * F_;
  #pragma unroll
  for (int m = 0; m < 4; m++){
    int rbase = row0 + wr*64 + m*16 + (lane >> 4) * 4;
    float lav[4];
    #pragma unroll
    for (int r = 0; r < 4; r++) lav[r] = la[rbase + r];
    #pragma unroll
    for (int n = 0; n < 4; n++){
      int col = col0 + wc*64 + n*16 + (lane & 15);
      float rav = rab[col];
      float bvv = bv[col];
      #pragma unroll
      for (int r = 0; r < 4; r++){
        int row = rbase + r;
        float v = acc[m][n][r] * scale + bvv;
        size_t idx = (size_t)row * N_ + col;
        Out[idx] = oma * X[idx] + a * lav[r] * v * rav;
      }
    }
  }
}

// ---------- launch ----------
extern "C" void kernel_launch(void* const* d_in, const int* in_sizes, int n_in,
                              void* d_out, int out_size, void* d_ws, size_t ws_size,
                              hipStream_t stream){
  const float* x     = (const float*)d_in[0];
  const float* Wv    = (const float*)d_in[3];
  const float* bv    = (const float*)d_in[4];
  const float* wl    = (const float*)d_in[5];
  const float* bl    = (const float*)d_in[6];
  const float* wrt   = (const float*)d_in[7];
  const float* br    = (const float*)d_in[8];
  const float* alpha = (const float*)d_in[9];
  float* out = (float*)d_out;

  char* ws = (char*)d_ws;
  unsigned short* XH = (unsigned short*)(ws);              // 67,108,864 B
  unsigned short* BT = (unsigned short*)(ws + 67108864);   //  8,388,608 B
  float* la_raw = (float*)(ws + 75497472);                 // 65,536 B
  float* la     = (float*)(ws + 75563008);                 // 65,536 B
  float* ra_raw = (float*)(ws + 75628544);                 // 65,536 B
  float* ra     = (float*)(ws + 75694080);                 // 65,536 B
  float* part   = (float*)(ws + 75759616);                 // 16,384 B
  float* scalep = (float*)(ws + 75776000);                 //    256 B

  hipMemsetAsync(ra_raw, 0, B_ * F_ * sizeof(float), stream);
  k_abs1<<<4096, 256, 0, stream>>>(Wv, part);
  k_abs2<<<1, 256, 0, stream>>>(part, scalep);
  k_quantT<<<dim3(F_/32, F_/32), 256, 0, stream>>>(Wv, BT, scalep);
  k_front<<<M_/32, 256, 0, stream>>>(x, wl, bl, wrt, XH, la_raw, ra_raw);
  k_ln<<<16, 256, 0, stream>>>(la_raw, ra_raw, br, la, ra);
  k_gemm<<<2048, 256, 0, stream>>>(XH, BT, x, la, ra, bv, alpha, scalep, out);
}